// Round 1
// baseline (253.642 us; speedup 1.0000x reference)
//
#include <hip/hip_runtime.h>
#include <hip/hip_bf16.h>
#include <stdint.h>

#define NHEADS 8
#define SEQ    4096
#define DIM    128
#define TOK    32768

typedef __attribute__((ext_vector_type(4))) float  f32x4;
typedef __attribute__((ext_vector_type(8))) short  bf16x8;
typedef __attribute__((ext_vector_type(8))) unsigned short u16x8;

__device__ __forceinline__ unsigned short f32_to_bf16(float f) {
  union { float f; unsigned int u; } cv; cv.f = f;
  unsigned int u = cv.u;
  u += 0x7FFFu + ((u >> 16) & 1u);   // round-to-nearest-even
  return (unsigned short)(u >> 16);
}

// ---------------------------------------------------------------------------
// Kernel A: qkv = query @ W_qkv + b_qkv; split into per-head bf16 tensors.
//   Qh[h][s][e] = (q + u_bias[h]) * 1/sqrt(128)   (scale folded in)
//   Kh[h][s][e] = (k + v_bias[h])
//   Vh[h][s][e] = v
// token t -> h = t & 7, s = t >> 3
// ---------------------------------------------------------------------------
__global__ __launch_bounds__(256) void qkv_proj_kernel(
    const float* __restrict__ qin, const float* __restrict__ W,
    const float* __restrict__ bqkv, const float* __restrict__ ubias,
    const float* __restrict__ vbias,
    unsigned short* __restrict__ Qh, unsigned short* __restrict__ Kh,
    unsigned short* __restrict__ Vh) {
  __shared__ float Qt[64][129];   // +1 pad -> conflict-free column reads
  __shared__ float Wt[128][32];

  const int tid  = threadIdx.x;
  const int tok0 = blockIdx.x * 64;

  // stage 64x128 query tile (scalar LDS writes keep the padded stride)
  #pragma unroll
  for (int c = 0; c < 8; ++c) {
    int idx = tid + c * 256;          // 2048 float4 chunks
    int t   = idx >> 5;
    int e4  = idx & 31;
    f32x4 v = *reinterpret_cast<const f32x4*>(qin + (size_t)(tok0 + t) * DIM + e4 * 4);
    Qt[t][e4 * 4 + 0] = v[0];
    Qt[t][e4 * 4 + 1] = v[1];
    Qt[t][e4 * 4 + 2] = v[2];
    Qt[t][e4 * 4 + 3] = v[3];
  }

  const int t  = tid & 63;
  const int cg = tid >> 6;            // 0..3 -> 8-col group
  const int gt = tok0 + t;
  const int h  = gt & 7;
  const int s  = gt >> 3;
  const float scale = 0.088388347648318447f;  // 1/sqrt(128)

  for (int jc = 0; jc < 12; ++jc) {   // 12 chunks of 32 output cols (384 total)
    __syncthreads();                  // Qt ready (jc==0) / Wt reuse safe (jc>0)
    #pragma unroll
    for (int c = 0; c < 4; ++c) {
      int idx = tid + c * 256;        // 1024 float4 chunks
      int e   = idx >> 3;
      int c4  = idx & 7;
      *reinterpret_cast<f32x4*>(&Wt[e][c4 * 4]) =
          *reinterpret_cast<const f32x4*>(W + (size_t)e * 384 + jc * 32 + c4 * 4);
    }
    __syncthreads();

    float acc[8] = {0.f, 0.f, 0.f, 0.f, 0.f, 0.f, 0.f, 0.f};
    #pragma unroll 4
    for (int e = 0; e < DIM; ++e) {
      float qv = Qt[t][e];            // conflict-free (stride 129)
      #pragma unroll
      for (int c = 0; c < 8; ++c) acc[c] += qv * Wt[e][cg * 8 + c];  // broadcast
    }

    const int j0 = jc * 32 + cg * 8;  // wave-uniform -> uniform branch below
    u16x8 ov;
    if (j0 < 128) {
      #pragma unroll
      for (int c = 0; c < 8; ++c)
        ov[c] = f32_to_bf16((acc[c] + bqkv[j0 + c] + ubias[h * DIM + j0 + c]) * scale);
      *reinterpret_cast<u16x8*>(Qh + ((size_t)h * SEQ + s) * DIM + j0) = ov;
    } else if (j0 < 256) {
      const int e0 = j0 - 128;
      #pragma unroll
      for (int c = 0; c < 8; ++c)
        ov[c] = f32_to_bf16(acc[c] + bqkv[j0 + c] + vbias[h * DIM + e0 + c]);
      *reinterpret_cast<u16x8*>(Kh + ((size_t)h * SEQ + s) * DIM + e0) = ov;
    } else {
      const int e0 = j0 - 256;
      #pragma unroll
      for (int c = 0; c < 8; ++c)
        ov[c] = f32_to_bf16(acc[c] + bqkv[j0 + c]);
      *reinterpret_cast<u16x8*>(Vh + ((size_t)h * SEQ + s) * DIM + e0) = ov;
    }
  }
}

// ---------------------------------------------------------------------------
// Kernel A2: Vt[h][e][s] = Vh[h][s][e]  (64x64 LDS tiles, vector global I/O)
// ---------------------------------------------------------------------------
__global__ __launch_bounds__(256) void v_transpose_kernel(
    const unsigned short* __restrict__ Vh, unsigned short* __restrict__ Vt) {
  __shared__ unsigned short tile[64][66];   // stride 66 breaks pow2 conflicts
  const int h   = blockIdx.z;
  const int st  = blockIdx.y;               // s tile (64 wide)
  const int et  = blockIdx.x;               // e tile (64 wide)
  const int tid = threadIdx.x;

  #pragma unroll
  for (int c = 0; c < 2; ++c) {
    int idx = tid + c * 256;
    int sl  = idx >> 3;
    int e8  = idx & 7;
    u16x8 v = *reinterpret_cast<const u16x8*>(
        Vh + ((size_t)h * SEQ + st * 64 + sl) * DIM + et * 64 + e8 * 8);
    #pragma unroll
    for (int j = 0; j < 8; ++j) tile[sl][e8 * 8 + j] = v[j];
  }
  __syncthreads();
  #pragma unroll
  for (int c = 0; c < 2; ++c) {
    int idx = tid + c * 256;
    int el  = idx >> 3;
    int s8  = idx & 7;
    u16x8 v;
    #pragma unroll
    for (int j = 0; j < 8; ++j) v[j] = tile[s8 * 8 + j][el];
    *reinterpret_cast<u16x8*>(
        Vt + ((size_t)h * DIM + et * 64 + el) * SEQ + st * 64 + s8 * 8) = v;
  }
}

// ---------------------------------------------------------------------------
// Kernel B: flash attention. Block = head h, 64 q-rows; 4 waves x 16 rows.
// KV tiles of 64 staged in LDS (XOR-swizzled). Online softmax in registers.
// mfma_f32_16x16x32_bf16:
//   A: lane holds A[l&15][(l>>4)*8 + j]   (8 contiguous k)
//   B: lane holds B[(l>>4)*8 + j][l&15]
//   C/D: col = l&15, row = (l>>4)*4 + reg   [measured m89]
// ---------------------------------------------------------------------------
__global__ __launch_bounds__(256) void attn_fwd_kernel(
    const unsigned short* __restrict__ Qh, const unsigned short* __restrict__ Kh,
    const unsigned short* __restrict__ Vt, float* __restrict__ Out) {
  __shared__ unsigned short Kl[64 * 128];   // 16KB, byte ^= (key&7)<<4
  __shared__ unsigned short Vl[128 * 64];   // 16KB, rows = e, byte ^= (e&7)<<4
  __shared__ unsigned short Pl[4][16 * 64]; // 8KB, per wave, byte ^= (row&7)<<4

  const int tid  = threadIdx.x;
  const int lane = tid & 63;
  const int w    = tid >> 6;         // wave 0..3
  const int h    = blockIdx.x >> 6;
  const int qb   = blockIdx.x & 63;
  const int lr   = lane & 15;
  const int lg   = lane >> 4;

  // Q fragments for this wave's 16 rows (once; bf16, pre-scaled)
  bf16x8 qf[4];
  const unsigned short* qptr =
      Qh + ((size_t)h * SEQ + qb * 64 + w * 16 + lr) * DIM + lg * 8;
  #pragma unroll
  for (int kk = 0; kk < 4; ++kk)
    qf[kk] = *reinterpret_cast<const bf16x8*>(qptr + kk * 32);

  f32x4 acc[8];
  #pragma unroll
  for (int nt = 0; nt < 8; ++nt) acc[nt] = (f32x4)(0.0f);
  float m_r[4], l_r[4];
  #pragma unroll
  for (int r = 0; r < 4; ++r) { m_r[r] = -1e30f; l_r[r] = 0.0f; }

  char* KlB = reinterpret_cast<char*>(Kl);
  char* VlB = reinterpret_cast<char*>(Vl);
  char* PlB = reinterpret_cast<char*>(Pl[w]);

  for (int kt = 0; kt < SEQ / 64; ++kt) {
    __syncthreads();  // previous iteration's LDS reads done
    // stage K tile: 64 keys x 128 e
    #pragma unroll
    for (int c = 0; c < 4; ++c) {
      int idx = tid + c * 256;
      int row = idx >> 4;
      int c8  = idx & 15;
      bf16x8 v = *reinterpret_cast<const bf16x8*>(
          Kh + ((size_t)h * SEQ + kt * 64 + row) * DIM + c8 * 8);
      int bo = (row * 256 + c8 * 16) ^ ((row & 7) << 4);
      *reinterpret_cast<bf16x8*>(KlB + bo) = v;
    }
    // stage V^T tile: 128 e x 64 keys
    #pragma unroll
    for (int c = 0; c < 4; ++c) {
      int idx = tid + c * 256;
      int e   = idx >> 3;
      int c8  = idx & 7;
      bf16x8 v = *reinterpret_cast<const bf16x8*>(
          Vt + ((size_t)h * DIM + e) * SEQ + kt * 64 + c8 * 8);
      int bo = (e * 128 + c8 * 16) ^ ((e & 7) << 4);
      *reinterpret_cast<bf16x8*>(VlB + bo) = v;
    }
    __syncthreads();

    // QK^T: scores 16 x 64 as 4 col-tiles
    f32x4 sc[4];
    #pragma unroll
    for (int ct = 0; ct < 4; ++ct) {
      f32x4 a = (f32x4)(0.0f);
      #pragma unroll
      for (int kk = 0; kk < 4; ++kk) {
        int row = ct * 16 + lr;                       // key index
        int bo  = (row * 256 + (kk * 32 + lg * 8) * 2) ^ ((row & 7) << 4);
        bf16x8 kf = *reinterpret_cast<const bf16x8*>(KlB + bo);
        a = __builtin_amdgcn_mfma_f32_16x16x32_bf16(qf[kk], kf, a, 0, 0, 0);
      }
      sc[ct] = a;
    }

    // online softmax (rows = lg*4 + r; cols across the 16-lane group)
    #pragma unroll
    for (int r = 0; r < 4; ++r) {
      float mx = fmaxf(fmaxf(sc[0][r], sc[1][r]), fmaxf(sc[2][r], sc[3][r]));
      mx = fmaxf(mx, __shfl_xor(mx, 1));
      mx = fmaxf(mx, __shfl_xor(mx, 2));
      mx = fmaxf(mx, __shfl_xor(mx, 4));
      mx = fmaxf(mx, __shfl_xor(mx, 8));
      float mn   = fmaxf(m_r[r], mx);
      float corr = __expf(m_r[r] - mn);
      m_r[r] = mn;
      float ps = 0.0f;
      const int row = lg * 4 + r;
      #pragma unroll
      for (int ct = 0; ct < 4; ++ct) {
        float p = __expf(sc[ct][r] - mn);
        ps += p;
        int col = ct * 16 + lr;
        int bo  = (row * 128 + col * 2) ^ ((row & 7) << 4);
        *reinterpret_cast<unsigned short*>(PlB + bo) = f32_to_bf16(p);
      }
      ps += __shfl_xor(ps, 1);
      ps += __shfl_xor(ps, 2);
      ps += __shfl_xor(ps, 4);
      ps += __shfl_xor(ps, 8);
      l_r[r] = l_r[r] * corr + ps;
      #pragma unroll
      for (int nt = 0; nt < 8; ++nt) acc[nt][r] *= corr;
    }

    // P writes -> P reads are same-wave: drain LDS queue
    asm volatile("s_waitcnt lgkmcnt(0)" ::: "memory");

    // PV: O(16x128) += P(16x64) @ V(64x128)
    #pragma unroll
    for (int kk2 = 0; kk2 < 2; ++kk2) {
      int bo = (lr * 128 + (kk2 * 32 + lg * 8) * 2) ^ ((lr & 7) << 4);
      bf16x8 pf = *reinterpret_cast<const bf16x8*>(PlB + bo);
      #pragma unroll
      for (int nt = 0; nt < 8; ++nt) {
        int e   = nt * 16 + lr;
        int bo2 = (e * 128 + (kk2 * 32 + lg * 8) * 2) ^ ((e & 7) << 4);
        bf16x8 vf = *reinterpret_cast<const bf16x8*>(VlB + bo2);
        acc[nt] = __builtin_amdgcn_mfma_f32_16x16x32_bf16(pf, vf, acc[nt], 0, 0, 0);
      }
    }
  }

  // epilogue: normalize and store f32
  #pragma unroll
  for (int r = 0; r < 4; ++r) {
    float inv = 1.0f / l_r[r];
    int row = qb * 64 + w * 16 + lg * 4 + r;
    float* op = Out + ((size_t)h * SEQ + row) * DIM + lr;
    #pragma unroll
    for (int nt = 0; nt < 8; ++nt) op[nt * 16] = acc[nt][r] * inv;
  }
}

// ---------------------------------------------------------------------------
extern "C" void kernel_launch(void* const* d_in, const int* in_sizes, int n_in,
                              void* d_out, int out_size, void* d_ws, size_t ws_size,
                              hipStream_t stream) {
  (void)in_sizes; (void)n_in; (void)out_size; (void)ws_size;
  const float* query = (const float*)d_in[0];
  // d_in[1] = key, d_in[2] = value : unused by the module
  const float* W_qkv = (const float*)d_in[3];
  const float* b_qkv = (const float*)d_in[4];
  const float* u_bias = (const float*)d_in[5];
  const float* v_bias = (const float*)d_in[6];
  float* out = (float*)d_out;

  const size_t per = (size_t)NHEADS * SEQ * DIM;   // 4M elems
  unsigned short* Qh = (unsigned short*)d_ws;
  unsigned short* Kh = Qh + per;
  unsigned short* Vh = Kh + per;
  unsigned short* Vt = Vh + per;                   // 32MB total ws use

  qkv_proj_kernel<<<dim3(TOK / 64), dim3(256), 0, stream>>>(
      query, W_qkv, b_qkv, u_bias, v_bias, Qh, Kh, Vh);
  v_transpose_kernel<<<dim3(2, 64, 8), dim3(256), 0, stream>>>(Vh, Vt);
  attn_fwd_kernel<<<dim3(NHEADS * 64), dim3(256), 0, stream>>>(Qh, Kh, Vt, out);
}

// Round 2
// 211.028 us; speedup vs baseline: 1.2019x; 1.2019x over previous
//
#include <hip/hip_runtime.h>
#include <hip/hip_bf16.h>
#include <stdint.h>

#define NHEADS 8
#define SEQ    4096
#define DIM    128
#define TOK    32768

typedef __attribute__((ext_vector_type(4))) float  f32x4;
typedef __attribute__((ext_vector_type(8))) short  bf16x8;
typedef __attribute__((ext_vector_type(8))) unsigned short u16x8;
typedef __attribute__((ext_vector_type(2))) unsigned int u32x2;

__device__ __forceinline__ unsigned short f32_to_bf16(float f) {
  union { float f; unsigned int u; } cv; cv.f = f;
  unsigned int u = cv.u;
  u += 0x7FFFu + ((u >> 16) & 1u);   // round-to-nearest-even
  return (unsigned short)(u >> 16);
}
__device__ __forceinline__ unsigned int pack_bf16(float lo, float hi) {
  return (unsigned int)f32_to_bf16(lo) | ((unsigned int)f32_to_bf16(hi) << 16);
}

// ---------------------------------------------------------------------------
// Kernel A: qkv = query @ W_qkv + b_qkv; split into per-head bf16 tensors.
//   Qh[h][s][e] = (q + u_bias[h]) * (log2(e)/sqrt(128))   (exp2-domain scale)
//   Kh[h][s][e] = (k + v_bias[h])
//   Vh[h][s][e] = v
// token t -> h = t & 7, s = t >> 3
// ---------------------------------------------------------------------------
__global__ __launch_bounds__(256) void qkv_proj_kernel(
    const float* __restrict__ qin, const float* __restrict__ W,
    const float* __restrict__ bqkv, const float* __restrict__ ubias,
    const float* __restrict__ vbias,
    unsigned short* __restrict__ Qh, unsigned short* __restrict__ Kh,
    unsigned short* __restrict__ Vh) {
  __shared__ float Qt[64][129];   // +1 pad -> conflict-free column reads
  __shared__ float Wt[128][32];

  const int tid  = threadIdx.x;
  const int tok0 = blockIdx.x * 64;

  #pragma unroll
  for (int c = 0; c < 8; ++c) {
    int idx = tid + c * 256;          // 2048 float4 chunks
    int t   = idx >> 5;
    int e4  = idx & 31;
    f32x4 v = *reinterpret_cast<const f32x4*>(qin + (size_t)(tok0 + t) * DIM + e4 * 4);
    Qt[t][e4 * 4 + 0] = v[0];
    Qt[t][e4 * 4 + 1] = v[1];
    Qt[t][e4 * 4 + 2] = v[2];
    Qt[t][e4 * 4 + 3] = v[3];
  }

  const int t  = tid & 63;
  const int cg = tid >> 6;            // 0..3 -> 8-col group
  const int gt = tok0 + t;
  const int h  = gt & 7;
  const int s  = gt >> 3;
  const float scale = 0.1275174309f;  // log2(e)/sqrt(128): exp2-domain

  for (int jc = 0; jc < 12; ++jc) {   // 12 chunks of 32 output cols (384 total)
    __syncthreads();
    #pragma unroll
    for (int c = 0; c < 4; ++c) {
      int idx = tid + c * 256;
      int e   = idx >> 3;
      int c4  = idx & 7;
      *reinterpret_cast<f32x4*>(&Wt[e][c4 * 4]) =
          *reinterpret_cast<const f32x4*>(W + (size_t)e * 384 + jc * 32 + c4 * 4);
    }
    __syncthreads();

    float acc[8] = {0.f, 0.f, 0.f, 0.f, 0.f, 0.f, 0.f, 0.f};
    #pragma unroll 4
    for (int e = 0; e < DIM; ++e) {
      float qv = Qt[t][e];
      #pragma unroll
      for (int c = 0; c < 8; ++c) acc[c] += qv * Wt[e][cg * 8 + c];
    }

    const int j0 = jc * 32 + cg * 8;  // wave-uniform branch below
    u16x8 ov;
    if (j0 < 128) {
      #pragma unroll
      for (int c = 0; c < 8; ++c)
        ov[c] = f32_to_bf16((acc[c] + bqkv[j0 + c] + ubias[h * DIM + j0 + c]) * scale);
      *reinterpret_cast<u16x8*>(Qh + ((size_t)h * SEQ + s) * DIM + j0) = ov;
    } else if (j0 < 256) {
      const int e0 = j0 - 128;
      #pragma unroll
      for (int c = 0; c < 8; ++c)
        ov[c] = f32_to_bf16(acc[c] + bqkv[j0 + c] + vbias[h * DIM + e0 + c]);
      *reinterpret_cast<u16x8*>(Kh + ((size_t)h * SEQ + s) * DIM + e0) = ov;
    } else {
      const int e0 = j0 - 256;
      #pragma unroll
      for (int c = 0; c < 8; ++c)
        ov[c] = f32_to_bf16(acc[c] + bqkv[j0 + c]);
      *reinterpret_cast<u16x8*>(Vh + ((size_t)h * SEQ + s) * DIM + e0) = ov;
    }
  }
}

// ---------------------------------------------------------------------------
// Kernel A2: Vt[h][e][s] = Vh[h][s][e]
// ---------------------------------------------------------------------------
__global__ __launch_bounds__(256) void v_transpose_kernel(
    const unsigned short* __restrict__ Vh, unsigned short* __restrict__ Vt) {
  __shared__ unsigned short tile[64][66];
  const int h   = blockIdx.z;
  const int st  = blockIdx.y;
  const int et  = blockIdx.x;
  const int tid = threadIdx.x;

  #pragma unroll
  for (int c = 0; c < 2; ++c) {
    int idx = tid + c * 256;
    int sl  = idx >> 3;
    int e8  = idx & 7;
    u16x8 v = *reinterpret_cast<const u16x8*>(
        Vh + ((size_t)h * SEQ + st * 64 + sl) * DIM + et * 64 + e8 * 8);
    #pragma unroll
    for (int j = 0; j < 8; ++j) tile[sl][e8 * 8 + j] = v[j];
  }
  __syncthreads();
  #pragma unroll
  for (int c = 0; c < 2; ++c) {
    int idx = tid + c * 256;
    int el  = idx >> 3;
    int s8  = idx & 7;
    u16x8 v;
    #pragma unroll
    for (int j = 0; j < 8; ++j) v[j] = tile[s8 * 8 + j][el];
    *reinterpret_cast<u16x8*>(
        Vt + ((size_t)h * DIM + et * 64 + el) * SEQ + st * 64 + s8 * 8) = v;
  }
}

// ---------------------------------------------------------------------------
// Kernel B: flash attention, SWAPPED operands (T12 mechanism).
// Block = 64 q-rows of one head; 4 waves x 16 rows; KV tiles of 64 in LDS.
//
// mfma_f32_16x16x32_bf16 fragment facts (validated by round-1 pass):
//   reading row-major LDS tile M at [row=lr][col=lg*8..+7] serves as
//   A-frag (A=M) or B-frag (B=M^T) identically.
//   C/D: col = lane&15, row = (lane>>4)*4 + reg.
//
// QK: mfma(A=K, B=Q^T) -> S[key][q]: lane holds S[ct*16+lg*4+r][q=lr]
//   => softmax reduction axis is LANE-LOCAL (16 regs) + 2 shuffles.
// PV: mfma(A=V^T, B=P^T) -> O[e][q]: lane holds O[q=lr][e=nt*16+lg*4+r]
//   => rescale factor applies directly; epilogue stores f32x4.
// Async-STAGE (T14): next tile's global loads issued before compute,
// LDS writes after the barrier.
// ---------------------------------------------------------------------------
__global__ __launch_bounds__(256) void attn_fwd_kernel(
    const unsigned short* __restrict__ Qh, const unsigned short* __restrict__ Kh,
    const unsigned short* __restrict__ Vt, float* __restrict__ Out) {
  __shared__ unsigned short Kl[64 * 128];   // 16KB, byte ^= (key&7)<<4
  __shared__ unsigned short Vl[128 * 64];   // 16KB, rows = e, byte ^= (e&7)<<4
  __shared__ unsigned short Pl[4][16 * 64]; // 8KB, per wave [q][key], ^= (q&7)<<4

  const int tid  = threadIdx.x;
  const int lane = tid & 63;
  const int w    = tid >> 6;
  const int h    = blockIdx.x & 7;   // head-per-XCD: all blocks of head h on XCD h
  const int qb   = blockIdx.x >> 3;
  const int lr   = lane & 15;
  const int lg   = lane >> 4;

  // Q fragments (B-operand): rows w*16+lr, pre-scaled by log2e/sqrt(128)
  bf16x8 qf[4];
  const unsigned short* qptr =
      Qh + ((size_t)h * SEQ + qb * 64 + w * 16 + lr) * DIM + lg * 8;
  #pragma unroll
  for (int kk = 0; kk < 4; ++kk)
    qf[kk] = *reinterpret_cast<const bf16x8*>(qptr + kk * 32);

  f32x4 acc[8];
  #pragma unroll
  for (int nt = 0; nt < 8; ++nt) acc[nt] = (f32x4)(0.0f);
  float m_r = -1e30f, l_r = 0.0f;

  char* KlB = reinterpret_cast<char*>(Kl);
  char* VlB = reinterpret_cast<char*>(Vl);
  char* PlB = reinterpret_cast<char*>(Pl[w]);

  const unsigned short* Kbase = Kh + (size_t)h * SEQ * DIM;
  const unsigned short* Vbase = Vt + (size_t)h * DIM * SEQ;

  bf16x8 kr[4], vr[4];   // prefetch registers (async-STAGE)

  auto load_tile = [&](int kt) {
    #pragma unroll
    for (int c = 0; c < 4; ++c) {
      int idx = tid + c * 256;
      int row = idx >> 4, c8 = idx & 15;
      kr[c] = *reinterpret_cast<const bf16x8*>(
          Kbase + (size_t)(kt * 64 + row) * DIM + c8 * 8);
    }
    #pragma unroll
    for (int c = 0; c < 4; ++c) {
      int idx = tid + c * 256;
      int e = idx >> 3, c8 = idx & 7;
      vr[c] = *reinterpret_cast<const bf16x8*>(
          Vbase + (size_t)e * SEQ + kt * 64 + c8 * 8);
    }
  };
  auto write_tile = [&]() {
    #pragma unroll
    for (int c = 0; c < 4; ++c) {
      int idx = tid + c * 256;
      int row = idx >> 4, c8 = idx & 15;
      int bo = (row * 256 + c8 * 16) ^ ((row & 7) << 4);
      *reinterpret_cast<bf16x8*>(KlB + bo) = kr[c];
    }
    #pragma unroll
    for (int c = 0; c < 4; ++c) {
      int idx = tid + c * 256;
      int e = idx >> 3, c8 = idx & 7;
      int bo = (e * 128 + c8 * 16) ^ ((e & 7) << 4);
      *reinterpret_cast<bf16x8*>(VlB + bo) = vr[c];
    }
  };

  load_tile(0);
  write_tile();
  __syncthreads();

  for (int kt = 0; kt < SEQ / 64; ++kt) {
    if (kt < SEQ / 64 - 1) load_tile(kt + 1);   // issue early; hide under compute

    // QK^T swapped: sc[ct][r] = S[key=ct*16+lg*4+r][q=lr]
    f32x4 sc[4];
    #pragma unroll
    for (int ct = 0; ct < 4; ++ct) {
      f32x4 a = (f32x4)(0.0f);
      #pragma unroll
      for (int kk = 0; kk < 4; ++kk) {
        int row = ct * 16 + lr;
        int bo  = (row * 256 + (kk * 32 + lg * 8) * 2) ^ ((row & 7) << 4);
        bf16x8 kf = *reinterpret_cast<const bf16x8*>(KlB + bo);
        a = __builtin_amdgcn_mfma_f32_16x16x32_bf16(kf, qf[kk], a, 0, 0, 0);
      }
      sc[ct] = a;
    }

    // online softmax: reduction lane-local + 2 shuffles
    float mx = sc[0][0];
    #pragma unroll
    for (int ct = 0; ct < 4; ++ct)
      #pragma unroll
      for (int r = 0; r < 4; ++r) mx = fmaxf(mx, sc[ct][r]);
    mx = fmaxf(mx, __shfl_xor(mx, 16));
    mx = fmaxf(mx, __shfl_xor(mx, 32));
    float mn   = fmaxf(m_r, mx);
    float corr = exp2f(m_r - mn);
    m_r = mn;

    float p[4][4];
    float ps = 0.0f;
    #pragma unroll
    for (int ct = 0; ct < 4; ++ct)
      #pragma unroll
      for (int r = 0; r < 4; ++r) {
        p[ct][r] = exp2f(sc[ct][r] - mn);
        ps += p[ct][r];
      }
    ps += __shfl_xor(ps, 16);
    ps += __shfl_xor(ps, 32);
    l_r = l_r * corr + ps;
    #pragma unroll
    for (int nt = 0; nt < 8; ++nt) acc[nt] *= corr;

    // P -> LDS: packed, 4x ds_write_b64 per lane
    #pragma unroll
    for (int ct = 0; ct < 4; ++ct) {
      u32x2 pw;
      pw[0] = pack_bf16(p[ct][0], p[ct][1]);
      pw[1] = pack_bf16(p[ct][2], p[ct][3]);
      int bo = (lr * 128 + ct * 32 + lg * 8) ^ ((lr & 7) << 4);
      *reinterpret_cast<u32x2*>(PlB + bo) = pw;
    }
    asm volatile("s_waitcnt lgkmcnt(0)" ::: "memory");  // same-wave P write->read

    // PV swapped: acc[nt][r] = O[q=lr][e=nt*16+lg*4+r]
    #pragma unroll
    for (int kk2 = 0; kk2 < 2; ++kk2) {
      int bo = (lr * 128 + (kk2 * 32 + lg * 8) * 2) ^ ((lr & 7) << 4);
      bf16x8 pf = *reinterpret_cast<const bf16x8*>(PlB + bo);
      #pragma unroll
      for (int nt = 0; nt < 8; ++nt) {
        int e   = nt * 16 + lr;
        int bo2 = (e * 128 + (kk2 * 32 + lg * 8) * 2) ^ ((e & 7) << 4);
        bf16x8 vf = *reinterpret_cast<const bf16x8*>(VlB + bo2);
        acc[nt] = __builtin_amdgcn_mfma_f32_16x16x32_bf16(vf, pf, acc[nt], 0, 0, 0);
      }
    }

    __syncthreads();                         // all waves done reading Kl/Vl
    if (kt < SEQ / 64 - 1) write_tile();     // regs -> LDS (vmcnt by compiler)
    __syncthreads();                         // tile ready
  }

  // epilogue: normalize, f32x4 stores
  const float inv = 1.0f / l_r;
  const int row = qb * 64 + w * 16 + lr;
  float* op = Out + ((size_t)h * SEQ + row) * DIM;
  #pragma unroll
  for (int nt = 0; nt < 8; ++nt) {
    f32x4 o = acc[nt] * inv;
    *reinterpret_cast<f32x4*>(op + nt * 16 + lg * 4) = o;
  }
}

// ---------------------------------------------------------------------------
extern "C" void kernel_launch(void* const* d_in, const int* in_sizes, int n_in,
                              void* d_out, int out_size, void* d_ws, size_t ws_size,
                              hipStream_t stream) {
  (void)in_sizes; (void)n_in; (void)out_size; (void)ws_size;
  const float* query = (const float*)d_in[0];
  const float* W_qkv = (const float*)d_in[3];
  const float* b_qkv = (const float*)d_in[4];
  const float* u_bias = (const float*)d_in[5];
  const float* v_bias = (const float*)d_in[6];
  float* out = (float*)d_out;

  const size_t per = (size_t)NHEADS * SEQ * DIM;   // 4M elems
  unsigned short* Qh = (unsigned short*)d_ws;
  unsigned short* Kh = Qh + per;
  unsigned short* Vh = Kh + per;
  unsigned short* Vt = Vh + per;                   // 32MB total ws use

  qkv_proj_kernel<<<dim3(TOK / 64), dim3(256), 0, stream>>>(
      query, W_qkv, b_qkv, u_bias, v_bias, Qh, Kh, Vh);
  v_transpose_kernel<<<dim3(2, 64, 8), dim3(256), 0, stream>>>(Vh, Vt);
  attn_fwd_kernel<<<dim3(NHEADS * 64), dim3(256), 0, stream>>>(Qh, Kh, Vt, out);
}